// Round 1
// baseline (1311.767 us; speedup 1.0000x reference)
//
#include <hip/hip_runtime.h>

typedef _Float16 f16;
typedef _Float16 f16x8 __attribute__((ext_vector_type(8)));
typedef float f32x4 __attribute__((ext_vector_type(4)));

typedef const __attribute__((address_space(1))) void GV;
typedef __attribute__((address_space(3))) void LV;

__device__ __forceinline__ void gload16(const void* g, void* l) {
  __builtin_amdgcn_global_load_lds((GV*)g, (LV*)l, 16, 0, 0);
}

// stage a [128][64] f16 tile (16KB). src rows: src[(row0+row)*ld + k0 + ...]
// XOR-swizzle: chunk ^= row&7 (applied on global SOURCE; LDS stays linear).
__device__ __forceinline__ void stage128x64(const f16* src, int row0, int ld, int k0,
                                            f16* lds, int tid) {
  int wid = tid >> 6;
#pragma unroll
  for (int q = 0; q < 4; ++q) {
    int lin = q * 4096 + tid * 16;
    int row = lin >> 7;
    int ch = (lin >> 4) & 7;
    int sch = ch ^ (row & 7);
    gload16(src + (size_t)(row0 + row) * ld + k0 + sch * 8,
            (char*)lds + q * 4096 + wid * 1024);
  }
}

// stage a [128][32] f16 tile (8KB). swizzle chunk ^= row&3.
__device__ __forceinline__ void stage128x32(const f16* src, int row0, int ld, int k0,
                                            f16* lds, int tid) {
  int wid = tid >> 6;
#pragma unroll
  for (int q = 0; q < 2; ++q) {
    int lin = q * 4096 + tid * 16;
    int row = lin >> 6;
    int ch = (lin >> 4) & 3;
    int sch = ch ^ (row & 3);
    gload16(src + (size_t)(row0 + row) * ld + k0 + sch * 8,
            (char*)lds + q * 4096 + wid * 1024);
  }
}

__device__ __forceinline__ f16x8 frag64(const f16* T, int row, int chunk) {
  int ch = chunk ^ (row & 7);
  return *(const f16x8*)((const char*)T + row * 128 + ch * 16);
}
__device__ __forceinline__ f16x8 frag32(const f16* T, int row, int chunk) {
  int ch = chunk ^ (row & 3);
  return *(const f16x8*)((const char*)T + row * 64 + ch * 16);
}

#define MFMA(a, b, c) __builtin_amdgcn_mfma_f32_16x16x32_f16(a, b, c, 0, 0, 0)

// C[m][n] = sum_k A[m][k] * B[n][k]   (both operands K-major)
// M=512, K=512, N = gridDim.x*128. Output: C + bx*65536 + (m0+row)*128 + c
__global__ __launch_bounds__(256, 2)
void gemm512(const f16* __restrict__ A, const f16* __restrict__ B,
             f16* __restrict__ C) {
  __shared__ __align__(16) char sm[34816];
  f16* As = (f16*)sm;
  f16* Bs = (f16*)(sm + 16384);
  const int tid = threadIdx.x;
  const int lane = tid & 63;
  const int g = lane >> 4, r = lane & 15;
  const int wid = tid >> 6;
  const int wm = (wid >> 1) * 64, wn = (wid & 1) * 64;
  const int m0 = blockIdx.y * 128;
  const int n0 = blockIdx.x * 128;

  f32x4 acc[4][4] = {};

  for (int kt = 0; kt < 8; ++kt) {
    stage128x64(A, m0, 512, kt * 64, As, tid);
    stage128x64(B, n0, 512, kt * 64, Bs, tid);
    __syncthreads();
#pragma unroll
    for (int kk = 0; kk < 2; ++kk) {
      f16x8 af[4], bf[4];
#pragma unroll
      for (int i = 0; i < 4; ++i) af[i] = frag64(As, wm + i * 16 + r, (kk << 2) | g);
#pragma unroll
      for (int j = 0; j < 4; ++j) bf[j] = frag64(Bs, wn + j * 16 + r, (kk << 2) | g);
#pragma unroll
      for (int i = 0; i < 4; ++i)
#pragma unroll
        for (int j = 0; j < 4; ++j)
          acc[i][j] = MFMA(af[i], bf[j], acc[i][j]);
    }
    __syncthreads();
  }
  // epilogue via LDS transpose for coalesced fp16 stores
  f16* Ct = (f16*)sm;
#pragma unroll
  for (int i = 0; i < 4; ++i)
#pragma unroll
    for (int j = 0; j < 4; ++j) {
      int col = wn + j * 16 + r;
#pragma unroll
      for (int q = 0; q < 4; ++q) {
        int row = wm + i * 16 + g * 4 + q;
        Ct[row * 136 + col] = (f16)acc[i][j][q];
      }
    }
  __syncthreads();
  f16* Cb = C + (size_t)blockIdx.x * 65536;
#pragma unroll
  for (int p = 0; p < 8; ++p) {
    int row = p * 16 + (tid >> 4);
    int c0 = (tid & 15) * 8;
    f16x8 v = *(const f16x8*)&Ct[row * 136 + c0];
    *(f16x8*)&Cb[(size_t)(m0 + row) * 128 + c0] = v;
  }
}

// gates: z = sig(GH@WzT^T + gxz), r = sig(GH@WrT^T + gxr); out ZT, RHT=r*h (transposed layout)
__global__ __launch_bounds__(256, 2)
void gates512(const f16* __restrict__ GH, const f16* __restrict__ WzT,
              const f16* __restrict__ WrT, const float* __restrict__ Wzf,
              const float* __restrict__ bz, const float* __restrict__ Wrf,
              const float* __restrict__ br, const f16* __restrict__ AX,
              const f16* __restrict__ HT, f16* __restrict__ RHT,
              f16* __restrict__ ZT, int t) {
  __shared__ __align__(16) char sm[38400];
  f16* As = (f16*)sm;
  f16* Wzs = (f16*)(sm + 8192);
  f16* Wrs = (f16*)(sm + 16384);
  f16* CtT = (f16*)sm;
  f16* AXs = (f16*)(sm + 34816);
  float* wz0 = (float*)(sm + 35328);
  float* wz1 = (float*)(sm + 35840);
  float* bzv = (float*)(sm + 36352);
  float* wr0 = (float*)(sm + 36864);
  float* wr1 = (float*)(sm + 37376);
  float* brv = (float*)(sm + 37888);

  const int tid = threadIdx.x;
  const int bid = blockIdx.x;
  const int b = bid >> 2, nc = bid & 3;
  const int r0 = bid * 128;
  const int lane = tid & 63, g = lane >> 4, r = lane & 15;
  const int wid = tid >> 6;
  const int wm = (wid >> 1) * 64, wn = (wid & 1) * 64;

  if (tid < 128) {
    int node = nc * 128 + tid;
    int cf = b * 48 + t * 2;
    const f16* p = AX + (size_t)(cf >> 7) * 65536 + node * 128 + (cf & 127);
    AXs[2 * tid] = p[0];
    AXs[2 * tid + 1] = p[1];
    wz0[tid] = Wzf[tid];
    wz1[tid] = Wzf[128 + tid];
    bzv[tid] = bz[tid];
    wr0[tid] = Wrf[tid];
    wr1[tid] = Wrf[128 + tid];
    brv[tid] = br[tid];
  }

  f32x4 az[4][4] = {}, ar[4][4] = {};
  for (int kt = 0; kt < 4; ++kt) {
    stage128x32(GH, r0, 128, kt * 32, As, tid);
    stage128x32(WzT, 0, 128, kt * 32, Wzs, tid);
    stage128x32(WrT, 0, 128, kt * 32, Wrs, tid);
    __syncthreads();
    f16x8 af[4], zf[4], rf[4];
#pragma unroll
    for (int i = 0; i < 4; ++i) af[i] = frag32(As, wm + i * 16 + r, g);
#pragma unroll
    for (int j = 0; j < 4; ++j) zf[j] = frag32(Wzs, wn + j * 16 + r, g);
#pragma unroll
    for (int j = 0; j < 4; ++j) rf[j] = frag32(Wrs, wn + j * 16 + r, g);
#pragma unroll
    for (int i = 0; i < 4; ++i)
#pragma unroll
      for (int j = 0; j < 4; ++j) {
        az[i][j] = MFMA(af[i], zf[j], az[i][j]);
        ar[i][j] = MFMA(af[i], rf[j], ar[i][j]);
      }
    __syncthreads();
  }
  const size_t base = (size_t)b * 65536 + nc * 128;
  // ---- Z pass ----
#pragma unroll
  for (int i = 0; i < 4; ++i)
#pragma unroll
    for (int j = 0; j < 4; ++j) {
      int hcol = wn + j * 16 + r;
#pragma unroll
      for (int q = 0; q < 4; ++q) {
        int nrow = wm + i * 16 + g * 4 + q;
        CtT[hcol * 136 + nrow] = (f16)az[i][j][q];
      }
    }
  __syncthreads();
#pragma unroll
  for (int p = 0; p < 8; ++p) {
    int hh = p * 16 + (tid >> 4);
    int nl0 = (tid & 15) * 8;
    f16x8 cv = *(const f16x8*)&CtT[hh * 136 + nl0];
    float w0 = wz0[hh], w1 = wz1[hh], bb = bzv[hh];
    f16x8 o;
#pragma unroll
    for (int e = 0; e < 8; ++e) {
      int nl = nl0 + e;
      float gx = (float)AXs[2 * nl] * w0 + (float)AXs[2 * nl + 1] * w1 + bb;
      float v = (float)cv[e] + gx;
      o[e] = (f16)(1.f / (1.f + expf(-v)));
    }
    *(f16x8*)&ZT[base + (size_t)hh * 512 + nl0] = o;
  }
  __syncthreads();
  // ---- R pass ----
#pragma unroll
  for (int i = 0; i < 4; ++i)
#pragma unroll
    for (int j = 0; j < 4; ++j) {
      int hcol = wn + j * 16 + r;
#pragma unroll
      for (int q = 0; q < 4; ++q) {
        int nrow = wm + i * 16 + g * 4 + q;
        CtT[hcol * 136 + nrow] = (f16)ar[i][j][q];
      }
    }
  __syncthreads();
#pragma unroll
  for (int p = 0; p < 8; ++p) {
    int hh = p * 16 + (tid >> 4);
    int nl0 = (tid & 15) * 8;
    f16x8 cv = *(const f16x8*)&CtT[hh * 136 + nl0];
    f16x8 hv = *(const f16x8*)&HT[base + (size_t)hh * 512 + nl0];
    float w0 = wr0[hh], w1 = wr1[hh], bb = brv[hh];
    f16x8 o;
#pragma unroll
    for (int e = 0; e < 8; ++e) {
      int nl = nl0 + e;
      float gx = (float)AXs[2 * nl] * w0 + (float)AXs[2 * nl + 1] * w1 + bb;
      float rv = 1.f / (1.f + expf(-((float)cv[e] + gx)));
      o[e] = (f16)(rv * (float)hv[e]);
    }
    *(f16x8*)&RHT[base + (size_t)hh * 512 + nl0] = o;
  }
}

// update: htilde = tanh(GHR@WhT^T + gxh); hnew = (1-z)h + z*htilde -> HTn (transposed)
__global__ __launch_bounds__(256, 2)
void update512(const f16* __restrict__ GHR, const f16* __restrict__ WhT,
               const float* __restrict__ Whf, const float* __restrict__ bh,
               const f16* __restrict__ AX, const f16* __restrict__ HT,
               const f16* __restrict__ ZT, f16* __restrict__ HTn, int t) {
  __shared__ __align__(16) char sm[36864];
  f16* As = (f16*)sm;
  f16* Whs = (f16*)(sm + 8192);
  f16* CtT = (f16*)sm;
  f16* AXs = (f16*)(sm + 34816);
  float* wh0 = (float*)(sm + 35328);
  float* wh1 = (float*)(sm + 35840);
  float* bhv = (float*)(sm + 36352);

  const int tid = threadIdx.x;
  const int bid = blockIdx.x;
  const int b = bid >> 2, nc = bid & 3;
  const int r0 = bid * 128;
  const int lane = tid & 63, g = lane >> 4, r = lane & 15;
  const int wid = tid >> 6;
  const int wm = (wid >> 1) * 64, wn = (wid & 1) * 64;

  if (tid < 128) {
    int node = nc * 128 + tid;
    int cf = b * 48 + t * 2;
    const f16* p = AX + (size_t)(cf >> 7) * 65536 + node * 128 + (cf & 127);
    AXs[2 * tid] = p[0];
    AXs[2 * tid + 1] = p[1];
    wh0[tid] = Whf[tid];
    wh1[tid] = Whf[128 + tid];
    bhv[tid] = bh[tid];
  }

  f32x4 ah[4][4] = {};
  for (int kt = 0; kt < 4; ++kt) {
    stage128x32(GHR, r0, 128, kt * 32, As, tid);
    stage128x32(WhT, 0, 128, kt * 32, Whs, tid);
    __syncthreads();
    f16x8 af[4], hf[4];
#pragma unroll
    for (int i = 0; i < 4; ++i) af[i] = frag32(As, wm + i * 16 + r, g);
#pragma unroll
    for (int j = 0; j < 4; ++j) hf[j] = frag32(Whs, wn + j * 16 + r, g);
#pragma unroll
    for (int i = 0; i < 4; ++i)
#pragma unroll
      for (int j = 0; j < 4; ++j)
        ah[i][j] = MFMA(af[i], hf[j], ah[i][j]);
    __syncthreads();
  }
#pragma unroll
  for (int i = 0; i < 4; ++i)
#pragma unroll
    for (int j = 0; j < 4; ++j) {
      int hcol = wn + j * 16 + r;
#pragma unroll
      for (int q = 0; q < 4; ++q) {
        int nrow = wm + i * 16 + g * 4 + q;
        CtT[hcol * 136 + nrow] = (f16)ah[i][j][q];
      }
    }
  __syncthreads();
  const size_t base = (size_t)b * 65536 + nc * 128;
#pragma unroll
  for (int p = 0; p < 8; ++p) {
    int hh = p * 16 + (tid >> 4);
    int nl0 = (tid & 15) * 8;
    f16x8 cv = *(const f16x8*)&CtT[hh * 136 + nl0];
    f16x8 zv = *(const f16x8*)&ZT[base + (size_t)hh * 512 + nl0];
    f16x8 hv = *(const f16x8*)&HT[base + (size_t)hh * 512 + nl0];
    float w0 = wh0[hh], w1 = wh1[hh], bb = bhv[hh];
    f16x8 o;
#pragma unroll
    for (int e = 0; e < 8; ++e) {
      int nl = nl0 + e;
      float gx = (float)AXs[2 * nl] * w0 + (float)AXs[2 * nl + 1] * w1 + bb;
      float ht = tanhf((float)cv[e] + gx);
      float z = (float)zv[e];
      o[e] = (f16)((1.f - z) * (float)hv[e] + z * ht);
    }
    *(f16x8*)&HTn[base + (size_t)hh * 512 + nl0] = o;
  }
}

__global__ void m12k(const float* __restrict__ E, const float* __restrict__ W1,
                     const float* __restrict__ W2, float* __restrict__ M1,
                     float* __restrict__ M2) {
  int idx = blockIdx.x * 256 + threadIdx.x;
  if (idx >= 16384) return;
  int which = idx >> 13;
  int rem = idx & 8191;
  int n = rem >> 4, j = rem & 15;
  const float* W = which ? W2 : W1;
  float s = 0.f;
#pragma unroll
  for (int k = 0; k < 16; ++k) s += E[n * 16 + k] * W[k * 16 + j];
  (which ? M2 : M1)[n * 16 + j] = s;
}

__global__ __launch_bounds__(256)
void softA(const float* __restrict__ M1, const float* __restrict__ M2,
           f16* __restrict__ A16) {
  __shared__ float M2s[8192];
  __shared__ float m1s[16];
  __shared__ float red[8];
  int i = blockIdx.x, tid = threadIdx.x;
  for (int q = tid; q < 8192; q += 256) M2s[q] = M2[q];
  if (tid < 16) m1s[tid] = M1[i * 16 + tid];
  __syncthreads();
  float s0 = 0.f, s1 = 0.f;
#pragma unroll
  for (int k = 0; k < 16; ++k) {
    float a = m1s[k];
    s0 += a * M2s[tid * 16 + k];
    s1 += a * M2s[(tid + 256) * 16 + k];
  }
  s0 = fmaxf(s0, 0.f);
  s1 = fmaxf(s1, 0.f);
  float m = fmaxf(s0, s1);
  for (int o = 32; o > 0; o >>= 1) m = fmaxf(m, __shfl_xor(m, o));
  if ((tid & 63) == 0) red[tid >> 6] = m;
  __syncthreads();
  m = fmaxf(fmaxf(red[0], red[1]), fmaxf(red[2], red[3]));
  float e0 = expf(s0 - m), e1 = expf(s1 - m);
  float ss = e0 + e1;
  for (int o = 32; o > 0; o >>= 1) ss += __shfl_xor(ss, o);
  __syncthreads();
  if ((tid & 63) == 0) red[4 + (tid >> 6)] = ss;
  __syncthreads();
  ss = (red[4] + red[5]) + (red[6] + red[7]);
  float inv = 1.f / ss;
  A16[(size_t)i * 512 + tid] = (f16)(e0 * inv);
  A16[(size_t)i * 512 + tid + 256] = (f16)(e1 * inv);
}

__global__ void wTk(const float* __restrict__ Wz, const float* __restrict__ Wr,
                    const float* __restrict__ Wh, f16* __restrict__ WzT,
                    f16* __restrict__ WrT, f16* __restrict__ WhT) {
  int idx = blockIdx.x * 256 + threadIdx.x;
  if (idx >= 49152) return;
  int w = idx / 16384;
  int rem = idx & 16383;
  int hp = rem >> 7, k = rem & 127;
  const float* S = (w == 0) ? Wz : ((w == 1) ? Wr : Wh);
  f16* D = (w == 0) ? WzT : ((w == 1) ? WrT : WhT);
  D[hp * 128 + k] = (f16)S[(2 + k) * 128 + hp];
}

__global__ void xTk(const float* __restrict__ X, f16* __restrict__ XTT) {
  int idx = blockIdx.x * 256 + threadIdx.x;
  if (idx >= 786432) return;
  int m = idx & 511;
  int bt = idx >> 9;
  float x0 = X[(size_t)idx * 2];
  float x1 = X[(size_t)idx * 2 + 1];
  XTT[(size_t)(bt * 2 + 0) * 512 + m] = (f16)x0;
  XTT[(size_t)(bt * 2 + 1) * 512 + m] = (f16)x1;
}

__global__ __launch_bounds__(256)
void head512(const f16* __restrict__ HT, const float* __restrict__ Whead,
             const float* __restrict__ bhead, float* __restrict__ out) {
  __shared__ float Ws[1536];
  __shared__ float bs[12];
  int b = blockIdx.x >> 1, half = blockIdx.x & 1;
  int tid = threadIdx.x;
  for (int q = tid; q < 1536; q += 256) Ws[q] = Whead[q];
  if (tid < 12) bs[tid] = bhead[tid];
  __syncthreads();
  int n = half * 256 + tid;
  float acc[12];
#pragma unroll
  for (int o = 0; o < 12; ++o) acc[o] = bs[o];
  for (int hh = 0; hh < 128; ++hh) {
    float v = (float)HT[(size_t)b * 65536 + hh * 512 + n];
#pragma unroll
    for (int o = 0; o < 12; ++o) acc[o] += v * Ws[hh * 12 + o];
  }
#pragma unroll
  for (int o = 0; o < 12; ++o) out[(size_t)b * 6144 + o * 512 + n] = acc[o];
}

extern "C" void kernel_launch(void* const* d_in, const int* in_sizes, int n_in,
                              void* d_out, int out_size, void* d_ws, size_t ws_size,
                              hipStream_t stream) {
  (void)in_sizes; (void)n_in; (void)out_size; (void)ws_size;
  const float* X = (const float*)d_in[0];
  const float* E = (const float*)d_in[1];
  const float* W1 = (const float*)d_in[2];
  const float* W2 = (const float*)d_in[3];
  const float* Wz = (const float*)d_in[4];
  const float* bz = (const float*)d_in[5];
  const float* Wr = (const float*)d_in[6];
  const float* br = (const float*)d_in[7];
  const float* Wh = (const float*)d_in[8];
  const float* bh = (const float*)d_in[9];
  const float* Whead = (const float*)d_in[10];
  const float* bhead = (const float*)d_in[11];
  float* out = (float*)d_out;
  char* ws = (char*)d_ws;

  f16* A16 = (f16*)(ws + 0);          // 512x512
  f16* XTT = (f16*)(ws + 524288);     // 3072x512
  f16* AX  = (f16*)(ws + 3670016);    // tiles [24][512][128]
  f16* Ha  = (f16*)(ws + 6815744);    // [64][128][512]
  f16* Hb  = (f16*)(ws + 15204352);
  f16* GH  = (f16*)(ws + 23592960);   // [64][512][128]
  f16* RHT = (f16*)(ws + 31981568);   // [64][128][512]
  f16* ZT  = (f16*)(ws + 40370176);
  f16* WzT = (f16*)(ws + 48758784);   // 128x128
  f16* WrT = (f16*)(ws + 48791552);
  f16* WhT = (f16*)(ws + 48824320);
  float* M1 = (float*)(ws + 48857088);
  float* M2 = (float*)(ws + 48889856);

  hipMemsetAsync(Ha, 0, 8388608, stream);
  m12k<<<64, 256, 0, stream>>>(E, W1, W2, M1, M2);
  softA<<<512, 256, 0, stream>>>(M1, M2, A16);
  wTk<<<192, 256, 0, stream>>>(Wz, Wr, Wh, WzT, WrT, WhT);
  xTk<<<3072, 256, 0, stream>>>(X, XTT);
  gemm512<<<dim3(24, 4), 256, 0, stream>>>(A16, XTT, AX);

  f16* hc = Ha;
  f16* hn = Hb;
  for (int t = 0; t < 24; ++t) {
    gemm512<<<dim3(64, 4), 256, 0, stream>>>(A16, hc, GH);
    gates512<<<256, 256, 0, stream>>>(GH, WzT, WrT, Wz, bz, Wr, br, AX, hc, RHT, ZT, t);
    gemm512<<<dim3(64, 4), 256, 0, stream>>>(A16, RHT, GH);
    update512<<<256, 256, 0, stream>>>(GH, WhT, Wh, bh, AX, hc, ZT, hn, t);
    f16* tmp = hc; hc = hn; hn = tmp;
  }
  head512<<<128, 256, 0, stream>>>(hc, Whead, bhead, out);
}

// Round 2
// 1216.679 us; speedup vs baseline: 1.0782x; 1.0782x over previous
//
#include <hip/hip_runtime.h>

typedef _Float16 f16;
typedef _Float16 f16x8 __attribute__((ext_vector_type(8)));
typedef float f32x4 __attribute__((ext_vector_type(4)));

typedef const __attribute__((address_space(1))) void GV;
typedef __attribute__((address_space(3))) void LV;

__device__ __forceinline__ void gload16(const void* g, void* l) {
  __builtin_amdgcn_global_load_lds((GV*)g, (LV*)l, 16, 0, 0);
}

// stage a [128][64] f16 tile (16KB). XOR-swizzle chunk^=row&7 applied on the
// global SOURCE address; LDS dest stays linear (global_load_lds requirement).
__device__ __forceinline__ void stage128x64(const f16* src, int row0, int ld, int k0,
                                            f16* lds, int tid) {
  int wid = tid >> 6;
#pragma unroll
  for (int q = 0; q < 4; ++q) {
    int lin = q * 4096 + tid * 16;
    int row = lin >> 7;
    int ch = (lin >> 4) & 7;
    int sch = ch ^ (row & 7);
    gload16(src + (size_t)(row0 + row) * ld + k0 + sch * 8,
            (char*)lds + q * 4096 + wid * 1024);
  }
}

__device__ __forceinline__ f16x8 frag64(const f16* T, int row, int chunk) {
  int ch = chunk ^ (row & 7);
  return *(const f16x8*)((const char*)T + row * 128 + ch * 16);
}

// 128x128 f16 tile with full-XOR swizzle (conflict-free per quarter-wave).
__device__ __forceinline__ f16x8 frag128(const f16* T, int row, int chunk) {
  int ch = chunk ^ (row & 15);
  return *(const f16x8*)((const char*)T + row * 256 + ch * 16);
}
__device__ __forceinline__ f16* elem128(f16* T, int row, int col) {
  return (f16*)((char*)T + row * 256 + (((col >> 3) ^ (row & 15)) << 4) + (col & 7) * 2);
}

#define MFMA(a, b, c) __builtin_amdgcn_mfma_f32_16x16x32_f16(a, b, c, 0, 0, 0)

// C[m][n] = sum_k A[m][k] * B[n][k]; M=512, N=gridDim.x*128 (used for AX only)
__global__ __launch_bounds__(256, 2)
void gemm512(const f16* __restrict__ A, const f16* __restrict__ B,
             f16* __restrict__ C) {
  __shared__ __align__(16) char sm[34816];
  f16* As = (f16*)sm;
  f16* Bs = (f16*)(sm + 16384);
  const int tid = threadIdx.x;
  const int lane = tid & 63;
  const int g = lane >> 4, r = lane & 15;
  const int wid = tid >> 6;
  const int wm = (wid >> 1) * 64, wn = (wid & 1) * 64;
  const int m0 = blockIdx.y * 128;
  const int n0 = blockIdx.x * 128;

  f32x4 acc[4][4] = {};

  for (int kt = 0; kt < 8; ++kt) {
    stage128x64(A, m0, 512, kt * 64, As, tid);
    stage128x64(B, n0, 512, kt * 64, Bs, tid);
    __syncthreads();
#pragma unroll
    for (int kk = 0; kk < 2; ++kk) {
      f16x8 af[4], bf[4];
#pragma unroll
      for (int i = 0; i < 4; ++i) af[i] = frag64(As, wm + i * 16 + r, (kk << 2) | g);
#pragma unroll
      for (int j = 0; j < 4; ++j) bf[j] = frag64(Bs, wn + j * 16 + r, (kk << 2) | g);
#pragma unroll
      for (int i = 0; i < 4; ++i)
#pragma unroll
        for (int j = 0; j < 4; ++j)
          acc[i][j] = MFMA(af[i], bf[j], acc[i][j]);
    }
    __syncthreads();
  }
  f16* Ct = (f16*)sm;
#pragma unroll
  for (int i = 0; i < 4; ++i)
#pragma unroll
    for (int j = 0; j < 4; ++j) {
      int col = wn + j * 16 + r;
#pragma unroll
      for (int q = 0; q < 4; ++q) {
        int row = wm + i * 16 + g * 4 + q;
        Ct[row * 136 + col] = (f16)acc[i][j][q];
      }
    }
  __syncthreads();
  f16* Cb = C + (size_t)blockIdx.x * 65536;
#pragma unroll
  for (int p = 0; p < 8; ++p) {
    int row = p * 16 + (tid >> 4);
    int c0 = (tid & 15) * 8;
    f16x8 v = *(const f16x8*)&Ct[row * 136 + c0];
    *(f16x8*)&Cb[(size_t)(m0 + row) * 128 + c0] = v;
  }
}

// Fused: g = A@h (tile [b, m0:m0+128, all 128 h]) -> z,r gates -> ZT, RHT=r*h
__global__ __launch_bounds__(256, 1)
void stepA(const f16* __restrict__ A16, const f16* __restrict__ HT,
           const f16* __restrict__ WzT, const f16* __restrict__ WrT,
           const float* __restrict__ Wzf, const float* __restrict__ bz,
           const float* __restrict__ Wrf, const float* __restrict__ br,
           const f16* __restrict__ AX, f16* __restrict__ RHT,
           f16* __restrict__ ZT, int t) {
  __shared__ __align__(16) char sm[36352];
  f16* As = (f16*)sm;            // 16KB (phase1)
  f16* Bs = (f16*)(sm + 16384);  // 16KB (phase1)
  f16* Gs = (f16*)sm;            // 32KB (phase2, reuse)
  f16* Ct = (f16*)sm;            // 32KB (epilogue, reuse)
  f16* AXs = (f16*)(sm + 32768); // 512B
  float* wp = (float*)(sm + 33280); // 6*512B

  const int tid = threadIdx.x;
  const int lane = tid & 63;
  const int g = lane >> 4, r = lane & 15;
  const int wid = tid >> 6;
  const int wm = (wid >> 1) * 64, wn = (wid & 1) * 64;
  const int bid = blockIdx.x;
  const int b = bid >> 2, nc = bid & 3;
  const int m0 = nc * 128;

  // preload gate-weight B-fragments into registers (latency hides under phase1)
  f16x8 wzf[4][4], wrf[4][4];
#pragma unroll
  for (int kk = 0; kk < 4; ++kk)
#pragma unroll
    for (int j = 0; j < 4; ++j) {
      int row = wn + j * 16 + r;
      int k0 = (kk * 4 + g) * 8;
      wzf[kk][j] = *(const f16x8*)&WzT[row * 128 + k0];
      wrf[kk][j] = *(const f16x8*)&WrT[row * 128 + k0];
    }
  if (tid < 128) {
    int node = m0 + tid;
    int cf = b * 48 + t * 2;
    const f16* p = AX + (size_t)(cf >> 7) * 65536 + node * 128 + (cf & 127);
    AXs[2 * tid] = p[0];
    AXs[2 * tid + 1] = p[1];
    wp[tid] = Wzf[tid];
    wp[128 + tid] = Wzf[128 + tid];
    wp[256 + tid] = bz[tid];
    wp[384 + tid] = Wrf[tid];
    wp[512 + tid] = Wrf[128 + tid];
    wp[640 + tid] = br[tid];
  }

  const f16* HTb = HT + (size_t)b * 65536;
  f32x4 accg[4][4] = {};
  for (int kt = 0; kt < 8; ++kt) {
    stage128x64(A16, m0, 512, kt * 64, As, tid);
    stage128x64(HTb, 0, 512, kt * 64, Bs, tid);
    __syncthreads();
#pragma unroll
    for (int kk = 0; kk < 2; ++kk) {
      f16x8 af[4], bf[4];
#pragma unroll
      for (int i = 0; i < 4; ++i) af[i] = frag64(As, wm + i * 16 + r, (kk << 2) | g);
#pragma unroll
      for (int j = 0; j < 4; ++j) bf[j] = frag64(Bs, wn + j * 16 + r, (kk << 2) | g);
#pragma unroll
      for (int i = 0; i < 4; ++i)
#pragma unroll
        for (int j = 0; j < 4; ++j)
          accg[i][j] = MFMA(af[i], bf[j], accg[i][j]);
    }
    __syncthreads();
  }
  // g tile -> LDS [node][h] f16, swizzled
#pragma unroll
  for (int i = 0; i < 4; ++i)
#pragma unroll
    for (int j = 0; j < 4; ++j)
#pragma unroll
      for (int q = 0; q < 4; ++q)
        *elem128(Gs, wm + i * 16 + g * 4 + q, wn + j * 16 + r) = (f16)accg[i][j][q];
  __syncthreads();
  // gate GEMMs (K=128): Z = G@WzT^T, R = G@WrT^T
  f32x4 az[4][4] = {}, ar[4][4] = {};
#pragma unroll
  for (int kk = 0; kk < 4; ++kk) {
    f16x8 af[4];
#pragma unroll
    for (int i = 0; i < 4; ++i) af[i] = frag128(Gs, wm + i * 16 + r, (kk << 2) | g);
#pragma unroll
    for (int i = 0; i < 4; ++i)
#pragma unroll
      for (int j = 0; j < 4; ++j) {
        az[i][j] = MFMA(af[i], wzf[kk][j], az[i][j]);
        ar[i][j] = MFMA(af[i], wrf[kk][j], ar[i][j]);
      }
  }
  __syncthreads();
  const size_t base = (size_t)b * 65536 + m0;
  // ---- Z pass ----
#pragma unroll
  for (int i = 0; i < 4; ++i)
#pragma unroll
    for (int j = 0; j < 4; ++j)
#pragma unroll
      for (int q = 0; q < 4; ++q)
        *elem128(Ct, wn + j * 16 + r, wm + i * 16 + g * 4 + q) = (f16)az[i][j][q];
  __syncthreads();
#pragma unroll
  for (int p = 0; p < 8; ++p) {
    int hh = p * 16 + (tid >> 4);
    int c = tid & 15, nl0 = c * 8;
    f16x8 cv = frag128(Ct, hh, c);
    float w0 = wp[hh], w1 = wp[128 + hh], bb = wp[256 + hh];
    f16x8 o;
#pragma unroll
    for (int e = 0; e < 8; ++e) {
      int nl = nl0 + e;
      float gx = (float)AXs[2 * nl] * w0 + (float)AXs[2 * nl + 1] * w1 + bb;
      o[e] = (f16)(1.f / (1.f + expf(-((float)cv[e] + gx))));
    }
    *(f16x8*)&ZT[base + (size_t)hh * 512 + nl0] = o;
  }
  __syncthreads();
  // ---- R pass ----
#pragma unroll
  for (int i = 0; i < 4; ++i)
#pragma unroll
    for (int j = 0; j < 4; ++j)
#pragma unroll
      for (int q = 0; q < 4; ++q)
        *elem128(Ct, wn + j * 16 + r, wm + i * 16 + g * 4 + q) = (f16)ar[i][j][q];
  __syncthreads();
#pragma unroll
  for (int p = 0; p < 8; ++p) {
    int hh = p * 16 + (tid >> 4);
    int c = tid & 15, nl0 = c * 8;
    f16x8 cv = frag128(Ct, hh, c);
    f16x8 hv = *(const f16x8*)&HT[base + (size_t)hh * 512 + nl0];
    float w0 = wp[384 + hh], w1 = wp[512 + hh], bb = wp[640 + hh];
    f16x8 o;
#pragma unroll
    for (int e = 0; e < 8; ++e) {
      int nl = nl0 + e;
      float gx = (float)AXs[2 * nl] * w0 + (float)AXs[2 * nl + 1] * w1 + bb;
      float rv = 1.f / (1.f + expf(-((float)cv[e] + gx)));
      o[e] = (f16)(rv * (float)hv[e]);
    }
    *(f16x8*)&RHT[base + (size_t)hh * 512 + nl0] = o;
  }
}

// Fused: gh = A@(r*h) -> h_tilde = tanh -> hnew = (1-z)h + z*h_tilde -> HTn
__global__ __launch_bounds__(256, 1)
void stepB(const f16* __restrict__ A16, const f16* __restrict__ RHT,
           const f16* __restrict__ WhT, const float* __restrict__ Whf,
           const float* __restrict__ bh, const f16* __restrict__ AX,
           const f16* __restrict__ HT, const f16* __restrict__ ZT,
           f16* __restrict__ HTn, int t) {
  __shared__ __align__(16) char sm[36352];
  f16* As = (f16*)sm;
  f16* Bs = (f16*)(sm + 16384);
  f16* Gs = (f16*)sm;
  f16* Ct = (f16*)sm;
  f16* AXs = (f16*)(sm + 32768);
  float* wp = (float*)(sm + 33280);

  const int tid = threadIdx.x;
  const int lane = tid & 63;
  const int g = lane >> 4, r = lane & 15;
  const int wid = tid >> 6;
  const int wm = (wid >> 1) * 64, wn = (wid & 1) * 64;
  const int bid = blockIdx.x;
  const int b = bid >> 2, nc = bid & 3;
  const int m0 = nc * 128;

  f16x8 whf[4][4];
#pragma unroll
  for (int kk = 0; kk < 4; ++kk)
#pragma unroll
    for (int j = 0; j < 4; ++j) {
      int row = wn + j * 16 + r;
      int k0 = (kk * 4 + g) * 8;
      whf[kk][j] = *(const f16x8*)&WhT[row * 128 + k0];
    }
  if (tid < 128) {
    int node = m0 + tid;
    int cf = b * 48 + t * 2;
    const f16* p = AX + (size_t)(cf >> 7) * 65536 + node * 128 + (cf & 127);
    AXs[2 * tid] = p[0];
    AXs[2 * tid + 1] = p[1];
    wp[tid] = Whf[tid];
    wp[128 + tid] = Whf[128 + tid];
    wp[256 + tid] = bh[tid];
  }

  const f16* Rb = RHT + (size_t)b * 65536;
  f32x4 accg[4][4] = {};
  for (int kt = 0; kt < 8; ++kt) {
    stage128x64(A16, m0, 512, kt * 64, As, tid);
    stage128x64(Rb, 0, 512, kt * 64, Bs, tid);
    __syncthreads();
#pragma unroll
    for (int kk = 0; kk < 2; ++kk) {
      f16x8 af[4], bf[4];
#pragma unroll
      for (int i = 0; i < 4; ++i) af[i] = frag64(As, wm + i * 16 + r, (kk << 2) | g);
#pragma unroll
      for (int j = 0; j < 4; ++j) bf[j] = frag64(Bs, wn + j * 16 + r, (kk << 2) | g);
#pragma unroll
      for (int i = 0; i < 4; ++i)
#pragma unroll
        for (int j = 0; j < 4; ++j)
          accg[i][j] = MFMA(af[i], bf[j], accg[i][j]);
    }
    __syncthreads();
  }
#pragma unroll
  for (int i = 0; i < 4; ++i)
#pragma unroll
    for (int j = 0; j < 4; ++j)
#pragma unroll
      for (int q = 0; q < 4; ++q)
        *elem128(Gs, wm + i * 16 + g * 4 + q, wn + j * 16 + r) = (f16)accg[i][j][q];
  __syncthreads();
  f32x4 ah[4][4] = {};
#pragma unroll
  for (int kk = 0; kk < 4; ++kk) {
    f16x8 af[4];
#pragma unroll
    for (int i = 0; i < 4; ++i) af[i] = frag128(Gs, wm + i * 16 + r, (kk << 2) | g);
#pragma unroll
    for (int i = 0; i < 4; ++i)
#pragma unroll
      for (int j = 0; j < 4; ++j)
        ah[i][j] = MFMA(af[i], whf[kk][j], ah[i][j]);
  }
  __syncthreads();
#pragma unroll
  for (int i = 0; i < 4; ++i)
#pragma unroll
    for (int j = 0; j < 4; ++j)
#pragma unroll
      for (int q = 0; q < 4; ++q)
        *elem128(Ct, wn + j * 16 + r, wm + i * 16 + g * 4 + q) = (f16)ah[i][j][q];
  __syncthreads();
  const size_t base = (size_t)b * 65536 + m0;
#pragma unroll
  for (int p = 0; p < 8; ++p) {
    int hh = p * 16 + (tid >> 4);
    int c = tid & 15, nl0 = c * 8;
    f16x8 cv = frag128(Ct, hh, c);
    f16x8 zv = *(const f16x8*)&ZT[base + (size_t)hh * 512 + nl0];
    f16x8 hv = *(const f16x8*)&HT[base + (size_t)hh * 512 + nl0];
    float w0 = wp[hh], w1 = wp[128 + hh], bb = wp[256 + hh];
    f16x8 o;
#pragma unroll
    for (int e = 0; e < 8; ++e) {
      int nl = nl0 + e;
      float gx = (float)AXs[2 * nl] * w0 + (float)AXs[2 * nl + 1] * w1 + bb;
      float ht = tanhf((float)cv[e] + gx);
      float z = (float)zv[e];
      o[e] = (f16)((1.f - z) * (float)hv[e] + z * ht);
    }
    *(f16x8*)&HTn[base + (size_t)hh * 512 + nl0] = o;
  }
}

__global__ void m12k(const float* __restrict__ E, const float* __restrict__ W1,
                     const float* __restrict__ W2, float* __restrict__ M1,
                     float* __restrict__ M2) {
  int idx = blockIdx.x * 256 + threadIdx.x;
  if (idx >= 16384) return;
  int which = idx >> 13;
  int rem = idx & 8191;
  int n = rem >> 4, j = rem & 15;
  const float* W = which ? W2 : W1;
  float s = 0.f;
#pragma unroll
  for (int k = 0; k < 16; ++k) s += E[n * 16 + k] * W[k * 16 + j];
  (which ? M2 : M1)[n * 16 + j] = s;
}

__global__ __launch_bounds__(256)
void softA(const float* __restrict__ M1, const float* __restrict__ M2,
           f16* __restrict__ A16) {
  __shared__ float M2s[8192];
  __shared__ float m1s[16];
  __shared__ float red[8];
  int i = blockIdx.x, tid = threadIdx.x;
  for (int q = tid; q < 8192; q += 256) M2s[q] = M2[q];
  if (tid < 16) m1s[tid] = M1[i * 16 + tid];
  __syncthreads();
  float s0 = 0.f, s1 = 0.f;
#pragma unroll
  for (int k = 0; k < 16; ++k) {
    float a = m1s[k];
    s0 += a * M2s[tid * 16 + k];
    s1 += a * M2s[(tid + 256) * 16 + k];
  }
  s0 = fmaxf(s0, 0.f);
  s1 = fmaxf(s1, 0.f);
  float m = fmaxf(s0, s1);
  for (int o = 32; o > 0; o >>= 1) m = fmaxf(m, __shfl_xor(m, o));
  if ((tid & 63) == 0) red[tid >> 6] = m;
  __syncthreads();
  m = fmaxf(fmaxf(red[0], red[1]), fmaxf(red[2], red[3]));
  float e0 = expf(s0 - m), e1 = expf(s1 - m);
  float ss = e0 + e1;
  for (int o = 32; o > 0; o >>= 1) ss += __shfl_xor(ss, o);
  __syncthreads();
  if ((tid & 63) == 0) red[4 + (tid >> 6)] = ss;
  __syncthreads();
  ss = (red[4] + red[5]) + (red[6] + red[7]);
  float inv = 1.f / ss;
  A16[(size_t)i * 512 + tid] = (f16)(e0 * inv);
  A16[(size_t)i * 512 + tid + 256] = (f16)(e1 * inv);
}

__global__ void wTk(const float* __restrict__ Wz, const float* __restrict__ Wr,
                    const float* __restrict__ Wh, f16* __restrict__ WzT,
                    f16* __restrict__ WrT, f16* __restrict__ WhT) {
  int idx = blockIdx.x * 256 + threadIdx.x;
  if (idx >= 49152) return;
  int w = idx / 16384;
  int rem = idx & 16383;
  int hp = rem >> 7, k = rem & 127;
  const float* S = (w == 0) ? Wz : ((w == 1) ? Wr : Wh);
  f16* D = (w == 0) ? WzT : ((w == 1) ? WrT : WhT);
  D[hp * 128 + k] = (f16)S[(2 + k) * 128 + hp];
}

__global__ void xTk(const float* __restrict__ X, f16* __restrict__ XTT) {
  int idx = blockIdx.x * 256 + threadIdx.x;
  if (idx >= 786432) return;
  int m = idx & 511;
  int bt = idx >> 9;
  float x0 = X[(size_t)idx * 2];
  float x1 = X[(size_t)idx * 2 + 1];
  XTT[(size_t)(bt * 2 + 0) * 512 + m] = (f16)x0;
  XTT[(size_t)(bt * 2 + 1) * 512 + m] = (f16)x1;
}

__global__ __launch_bounds__(256)
void head512(const f16* __restrict__ HT, const float* __restrict__ Whead,
             const float* __restrict__ bhead, float* __restrict__ out) {
  __shared__ float Ws[1536];
  __shared__ float bs[12];
  int b = blockIdx.x >> 1, half = blockIdx.x & 1;
  int tid = threadIdx.x;
  for (int q = tid; q < 1536; q += 256) Ws[q] = Whead[q];
  if (tid < 12) bs[tid] = bhead[tid];
  __syncthreads();
  int n = half * 256 + tid;
  float acc[12];
#pragma unroll
  for (int o = 0; o < 12; ++o) acc[o] = bs[o];
  for (int hh = 0; hh < 128; ++hh) {
    float v = (float)HT[(size_t)b * 65536 + hh * 512 + n];
#pragma unroll
    for (int o = 0; o < 12; ++o) acc[o] += v * Ws[hh * 12 + o];
  }
#pragma unroll
  for (int o = 0; o < 12; ++o) out[(size_t)b * 6144 + o * 512 + n] = acc[o];
}

extern "C" void kernel_launch(void* const* d_in, const int* in_sizes, int n_in,
                              void* d_out, int out_size, void* d_ws, size_t ws_size,
                              hipStream_t stream) {
  (void)in_sizes; (void)n_in; (void)out_size; (void)ws_size;
  const float* X = (const float*)d_in[0];
  const float* E = (const float*)d_in[1];
  const float* W1 = (const float*)d_in[2];
  const float* W2 = (const float*)d_in[3];
  const float* Wz = (const float*)d_in[4];
  const float* bz = (const float*)d_in[5];
  const float* Wr = (const float*)d_in[6];
  const float* br = (const float*)d_in[7];
  const float* Wh = (const float*)d_in[8];
  const float* bh = (const float*)d_in[9];
  const float* Whead = (const float*)d_in[10];
  const float* bhead = (const float*)d_in[11];
  float* out = (float*)d_out;
  char* ws = (char*)d_ws;

  f16* A16 = (f16*)(ws + 0);          // 512x512
  f16* XTT = (f16*)(ws + 524288);     // 3072x512
  f16* AX  = (f16*)(ws + 3670016);    // [24 tiles][512][128]
  f16* Ha  = (f16*)(ws + 6815744);    // [64][128][512]
  f16* Hb  = (f16*)(ws + 15204352);
  f16* RHT = (f16*)(ws + 23592960);   // [64][128][512]
  f16* ZT  = (f16*)(ws + 31981568);
  f16* WzT = (f16*)(ws + 40370176);   // 128x128 f16
  f16* WrT = (f16*)(ws + 40402944);
  f16* WhT = (f16*)(ws + 40435712);
  float* M1 = (float*)(ws + 40468480);
  float* M2 = (float*)(ws + 40501248);

  hipMemsetAsync(Ha, 0, 8388608, stream);
  m12k<<<64, 256, 0, stream>>>(E, W1, W2, M1, M2);
  softA<<<512, 256, 0, stream>>>(M1, M2, A16);
  wTk<<<192, 256, 0, stream>>>(Wz, Wr, Wh, WzT, WrT, WhT);
  xTk<<<3072, 256, 0, stream>>>(X, XTT);
  gemm512<<<dim3(24, 4), 256, 0, stream>>>(A16, XTT, AX);

  f16* hc = Ha;
  f16* hn = Hb;
  for (int t = 0; t < 24; ++t) {
    stepA<<<256, 256, 0, stream>>>(A16, hc, WzT, WrT, Wz, bz, Wr, br, AX, RHT, ZT, t);
    stepB<<<256, 256, 0, stream>>>(A16, RHT, WhT, Wh, bh, AX, hc, ZT, hn, t);
    f16* tmp = hc; hc = hn; hn = tmp;
  }
  head512<<<128, 256, 0, stream>>>(hc, Whead, bhead, out);
}